// Round 4
// baseline (13102.795 us; speedup 1.0000x reference)
//
#include <hip/hip_runtime.h>
#include <hip/hip_bf16.h>
#include <math.h>

typedef __hip_bfloat16 bf16;
typedef __bf16 bf16t;
typedef __attribute__((ext_vector_type(8))) __bf16 bf16x8;
typedef __attribute__((ext_vector_type(4))) __bf16 bf16x4;
typedef __attribute__((ext_vector_type(16))) float f32x16;

#define E_DIM 768
#define HEADS 12
#define DHEAD 64
#define LAYERS 12
#define NTOK 197
#define BATCH 64
#define EPSV 1e-5f

__device__ __forceinline__ void split8(float4 u0, float4 u1, bf16x8& hi, bf16x8& lo) {
    float f[8] = {u0.x, u0.y, u0.z, u0.w, u1.x, u1.y, u1.z, u1.w};
#pragma unroll
    for (int j = 0; j < 8; ++j) {
        __bf16 h = (__bf16)f[j];
        hi[j] = h;
        lo[j] = (__bf16)(f[j] - (float)h);
    }
}

// ---------------- weight prep: elementwise split (conv_w, already [N][K]) ----------
__global__ __launch_bounds__(256) void esplit_k(const float* __restrict__ in,
                                                bf16t* __restrict__ oh,
                                                bf16t* __restrict__ ol, int n) {
    int i = blockIdx.x * 256 + threadIdx.x;
    if (i < n) {
        float v = in[i];
        __bf16 h = (__bf16)v;
        oh[i] = h;
        ol[i] = (__bf16)(v - (float)h);
    }
}

// ---------------- weight prep: transpose [K][N] -> [N][K] + split hi/lo ----------
// grid: (K/32, N/32, nMat). 32x32 tile via LDS.
__global__ __launch_bounds__(256) void tsplit_k(
    const float* __restrict__ in, long inStride,
    bf16t* __restrict__ oh, bf16t* __restrict__ ol, long outStride,
    int K, int N) {
    int z = blockIdx.z;
    in += (long)z * inStride;
    oh += (long)z * outStride;
    ol += (long)z * outStride;
    __shared__ float tile[32][33];
    int k0 = blockIdx.x * 32, n0 = blockIdx.y * 32;
    int tx = threadIdx.x & 31, ty = threadIdx.x >> 5;
#pragma unroll
    for (int i = 0; i < 4; ++i) {
        int k = k0 + ty + 8 * i, n = n0 + tx;
        tile[ty + 8 * i][tx] = (k < K && n < N) ? in[(long)k * N + n] : 0.f;
    }
    __syncthreads();
#pragma unroll
    for (int i = 0; i < 4; ++i) {
        int n = n0 + ty + 8 * i, k = k0 + tx;
        if (n < N && k < K) {
            float v = tile[tx][ty + 8 * i];
            __bf16 h = (__bf16)v;
            oh[(long)n * K + k] = h;
            ol[(long)n * K + k] = (__bf16)(v - (float)h);
        }
    }
}

// ---------------- im2col for patch embedding (emits hi/lo bf16 planes) ----------
__global__ __launch_bounds__(256) void im2col_k(const float* __restrict__ x,
                                                bf16t* __restrict__ Ph,
                                                bf16t* __restrict__ Pl,
                                                int b0, int M) {
    int task = blockIdx.x * 256 + threadIdx.x;
    if (task >= M * 96) return;
    int m = task / 96;
    int kg = task - m * 96;
    int k0 = kg * 8;
    int c = k0 >> 8, py = (k0 >> 4) & 15, px = k0 & 15;
    int bl = m / 196, pidx = m - bl * 196;
    int ph = pidx / 14, pw = pidx - ph * 14;
    const float* src = x + ((size_t)((b0 + bl) * 3 + c) * 224 + (ph * 16 + py)) * 224
                         + pw * 16 + px;
    const float4* s4 = reinterpret_cast<const float4*>(src);
    bf16x8 hi, lo;
    split8(s4[0], s4[1], hi, lo);
    *reinterpret_cast<bf16x8*>(Ph + (size_t)m * 768 + k0) = hi;
    *reinterpret_cast<bf16x8*>(Pl + (size_t)m * 768 + k0) = lo;
}

__global__ void embed_cls(const float* __restrict__ cls, const float* __restrict__ pos,
                          float* __restrict__ h) {
    int b = blockIdx.x, e = threadIdx.x;
    h[(size_t)b * NTOK * 768 + e] = cls[e] + pos[e];
}

// ---------------- layernorm over E=768, emits split hi/lo bf16 ----------------
__global__ __launch_bounds__(256) void layernorm_k(
    const float* __restrict__ h, bf16t* __restrict__ yh, bf16t* __restrict__ yl,
    const float* __restrict__ s, const float* __restrict__ bsh) {
    int tok = blockIdx.x, t = threadIdx.x;
    const float* row = h + (size_t)tok * 768;
    float v0 = row[t], v1 = row[t + 256], v2 = row[t + 512];
    float s1 = v0 + v1 + v2;
    float s2 = v0 * v0 + v1 * v1 + v2 * v2;
#pragma unroll
    for (int off = 32; off; off >>= 1) {
        s1 += __shfl_xor(s1, off);
        s2 += __shfl_xor(s2, off);
    }
    __shared__ float r1[4], r2[4];
    int wv = t >> 6, ln = t & 63;
    if (ln == 0) { r1[wv] = s1; r2[wv] = s2; }
    __syncthreads();
    s1 = r1[0] + r1[1] + r1[2] + r1[3];
    s2 = r2[0] + r2[1] + r2[2] + r2[3];
    float mean = s1 * (1.f / 768.f);
    float var = s2 * (1.f / 768.f) - mean * mean;
    float rs = rsqrtf(var + EPSV);
    size_t base = (size_t)tok * 768;
#pragma unroll
    for (int c = 0; c < 3; ++c) {
        int idx = t + c * 256;
        float v = (c == 0) ? v0 : (c == 1) ? v1 : v2;
        float o = (v - mean) * rs * s[idx] + bsh[idx];
        __bf16 hh = (__bf16)o;
        yh[base + idx] = hh;
        yl[base + idx] = (__bf16)(o - (float)hh);
    }
}

// ---------------- MFMA helpers ----------------
__device__ __forceinline__ f32x16 mfma_bf16(bf16x8 a, bf16x8 b, f32x16 c) {
    return __builtin_amdgcn_mfma_f32_32x32x16_bf16(a, b, c, 0, 0, 0);
}
__device__ __forceinline__ f32x16 zero16() {
    f32x16 z;
#pragma unroll
    for (int i = 0; i < 16; ++i) z[i] = 0.f;
    return z;
}
__device__ __forceinline__ bf16x8 zbf8() {
    bf16x8 v;
#pragma unroll
    for (int i = 0; i < 8; ++i) v[i] = (__bf16)0.f;
    return v;
}
__device__ __forceinline__ unsigned pkbf(float a, float b) {
    unsigned short ua = __builtin_bit_cast(unsigned short, (__bf16)a);
    unsigned short ub = __builtin_bit_cast(unsigned short, (__bf16)b);
    return (unsigned)ua | ((unsigned)ub << 16);
}
// async global->LDS, 16 B per lane; LDS dest must be wave-contiguous (lane*16)
__device__ __forceinline__ void gld16(const bf16t* g, char* l) {
    __builtin_amdgcn_global_load_lds(
        (const __attribute__((address_space(1))) unsigned int*)g,
        (__attribute__((address_space(3))) unsigned int*)l, 16, 0, 0);
}

// ---------------- MFMA GEMM on pre-split operands ----------------
// C[m,n] = sum_k A[m,k]*W[k,n] (+bias)(+gelu)(+resid)
// A given as bf16 hi/lo planes [M][K]; W as hi/lo planes TRANSPOSED [N][K].
// 128x128 tile, BK=32, 4 waves, v_mfma_f32_32x32x16_bf16, global_load_lds staging.
// TERMS=3: AhWh + AhWl + AlWh ; TERMS=2: AhWh + AhWl.
// flags: 1=gelu, 8=embedOut (row remap + pos), 16=qkvOut (deinterleave Q/K/V^T)
#define PLANE 2064

template <typename CT, int TERMS>
__global__ __launch_bounds__(256, 2) void gemm_mfma(
    const bf16t* __restrict__ Ah, const bf16t* __restrict__ Al, int lda,
    const bf16t* __restrict__ Wh, const bf16t* __restrict__ Wl,
    const float* __restrict__ bias,
    const float* __restrict__ resid,
    CT* __restrict__ C, int ldc,
    int M, int K, int flags) {
    constexpr bool SPLIT_A = (TERMS >= 3);
    const int gelu = flags & 1, embedOut = flags & 8, qkvOut = flags & 16;
    const int n0 = blockIdx.x * 128, m0 = blockIdx.y * 128;
    const int t = threadIdx.x;

    size_t QKT = 0;
    if (qkvOut) QKT = (size_t)(M / 197) * 12 * 197 * 64;

    __shared__ __align__(16) char smem[SPLIT_A ? 4 * 8256 : 3 * 8256];
    char* sAh = smem;
    char* sWh = smem + 8256;
    char* sWl = smem + 16512;
    char* sAl = SPLIT_A ? smem + 24768 : smem;

    const int lane = t & 63, wv = t >> 6;
    const int wm = wv >> 1, wn = wv & 1;
    const int lr = lane & 31, lk = lane >> 5;

    // staging: wave wv covers kg = (wv>>1) and (wv>>1)+2, rows row0..row0+63
    const int kgA = wv >> 1;
    const int row0 = (wv & 1) * 64;
    int arow = m0 + row0 + lane; if (arow >= M) arow = M - 1;   // clamp: rows indep.
    const int wrow = n0 + row0 + lane;
    const bf16t* aS  = Ah + (size_t)arow * lda + kgA * 8;
    const bf16t* alS = SPLIT_A ? Al + (size_t)arow * lda + kgA * 8 : aS;
    const bf16t* wS  = Wh + (size_t)wrow * K + kgA * 8;
    const bf16t* wlS = Wl + (size_t)wrow * K + kgA * 8;
    char* dA  = sAh + kgA * PLANE + row0 * 16;
    char* dAl = sAl + kgA * PLANE + row0 * 16;
    char* dW  = sWh + kgA * PLANE + row0 * 16;
    char* dWl = sWl + kgA * PLANE + row0 * 16;

    const int arow0 = (wm * 64 + lr) * 16;
    const int brow0 = (wn * 64 + lr) * 16;
    f32x16 acc00 = zero16(), acc01 = zero16(), acc10 = zero16(), acc11 = zero16();

    for (int k0 = 0; k0 < K; k0 += 32) {
        __syncthreads();
        gld16(aS + k0,       dA);
        gld16(aS + k0 + 16,  dA + 2 * PLANE);
        gld16(wS + k0,       dW);
        gld16(wS + k0 + 16,  dW + 2 * PLANE);
        gld16(wlS + k0,      dWl);
        gld16(wlS + k0 + 16, dWl + 2 * PLANE);
        if constexpr (SPLIT_A) {
            gld16(alS + k0,      dAl);
            gld16(alS + k0 + 16, dAl + 2 * PLANE);
        }
        __syncthreads();   // compiler drains vmcnt before s_barrier
#pragma unroll
        for (int ks = 0; ks < 2; ++ks) {
            const int kg = ks * 2 + lk;
            const char* pa  = sAh + kg * PLANE;
            const char* pb  = sWh + kg * PLANE;
            const char* pbl = sWl + kg * PLANE;
            bf16x8 ah0 = *reinterpret_cast<const bf16x8*>(pa + arow0);
            bf16x8 ah1 = *reinterpret_cast<const bf16x8*>(pa + arow0 + 512);
            bf16x8 bh0 = *reinterpret_cast<const bf16x8*>(pb + brow0);
            bf16x8 bh1 = *reinterpret_cast<const bf16x8*>(pb + brow0 + 512);
            bf16x8 bl0 = *reinterpret_cast<const bf16x8*>(pbl + brow0);
            bf16x8 bl1 = *reinterpret_cast<const bf16x8*>(pbl + brow0 + 512);
            acc00 = mfma_bf16(ah0, bh0, acc00);
            acc01 = mfma_bf16(ah0, bh1, acc01);
            acc10 = mfma_bf16(ah1, bh0, acc10);
            acc11 = mfma_bf16(ah1, bh1, acc11);
            acc00 = mfma_bf16(ah0, bl0, acc00);
            acc01 = mfma_bf16(ah0, bl1, acc01);
            acc10 = mfma_bf16(ah1, bl0, acc10);
            acc11 = mfma_bf16(ah1, bl1, acc11);
            if constexpr (SPLIT_A) {
                const char* pal = sAl + kg * PLANE;
                bf16x8 al0 = *reinterpret_cast<const bf16x8*>(pal + arow0);
                bf16x8 al1 = *reinterpret_cast<const bf16x8*>(pal + arow0 + 512);
                acc00 = mfma_bf16(al0, bh0, acc00);
                acc01 = mfma_bf16(al0, bh1, acc01);
                acc10 = mfma_bf16(al1, bh0, acc10);
                acc11 = mfma_bf16(al1, bh1, acc11);
            }
        }
    }

    const int gcol0 = n0 + wn * 64 + lr;
#define EPILOG(ACC, MF, NF)                                                         \
    {                                                                               \
        int gcol = gcol0 + (NF) * 32;                                               \
        float bv = bias[gcol];                                                      \
        int hh2 = gcol / 192;                                                       \
        int k2 = gcol - 192 * hh2;                                                  \
        int d2 = k2 / 3;                                                            \
        int r2 = k2 - 3 * d2;                                                       \
        _Pragma("unroll")                                                           \
        for (int r = 0; r < 16; ++r) {                                              \
            int grow = m0 + wm * 64 + (MF) * 32 + (r & 3) + 8 * (r >> 2) + 4 * lk;  \
            if (grow < M) {                                                         \
                float val = ACC[r] + bv;                                            \
                if (gelu) val = 0.5f * val * (1.f + erff(val * 0.70710678f));       \
                if (qkvOut) {                                                       \
                    int b2 = grow / 197, n2 = grow - 197 * b2;                      \
                    int bh2 = b2 * 12 + hh2;                                        \
                    if (r2 == 2)                                                    \
                        C[2 * QKT + ((size_t)bh2 * 64 + d2) * 208 + n2] = (CT)val;  \
                    else                                                            \
                        C[(r2 ? QKT : 0) + ((size_t)bh2 * 197 + n2) * 64 + d2] = (CT)val; \
                } else if (embedOut) {                                              \
                    int bl2 = grow / 196;                                           \
                    int pidx = grow - bl2 * 196;                                    \
                    val += resid[(size_t)(pidx + 1) * 768 + gcol];                  \
                    C[((size_t)bl2 * 197 + pidx + 1) * ldc + gcol] = (CT)val;       \
                } else {                                                            \
                    if (resid) val += resid[(size_t)grow * ldc + gcol];             \
                    C[(size_t)grow * ldc + gcol] = (CT)val;                         \
                }                                                                   \
            }                                                                       \
        }                                                                           \
    }
    EPILOG(acc00, 0, 0)
    EPILOG(acc01, 0, 1)
    EPILOG(acc10, 1, 0)
    EPILOG(acc11, 1, 1)
#undef EPILOG
}

// ---------------- MFMA fused attention (unchanged from round 3) ----------------
#define AKOFF 0
#define AVOFF 28672
#define AOOFF 61440
#define AOSTR 152
#define AOWAVE 4864

__global__ __launch_bounds__(256) void attn_mfma(
    const bf16t* __restrict__ Qb, const bf16t* __restrict__ Kb,
    const bf16t* __restrict__ Vg, bf16t* __restrict__ att) {
    __shared__ __align__(16) char lds[80896];
    const int bh = blockIdx.x;
    const int b = bh / 12, h = bh - b * 12;
    const int t = threadIdx.x;
    const int lane = t & 63, wv = t >> 6;
    const int lr = lane & 31, lk = lane >> 5;
    const int xorv = (lr & 7) << 4;

    {
        const bf16t* kb = Kb + (size_t)bh * 197 * 64;
#pragma unroll
        for (int c = 0; c < 7; ++c) {
            int idx = c * 256 + t;
            int row = idx >> 3, d8 = idx & 7;
            bf16x8 v = zbf8();
            if (row < 197) v = *(const bf16x8*)(kb + (size_t)row * 64 + d8 * 8);
            *(bf16x8*)(lds + AKOFF + row * 128 + ((d8 * 16) ^ ((row & 7) << 4))) = v;
        }
    }
    {
        const bf16t* vb = Vg + (size_t)bh * 64 * 208;
#pragma unroll
        for (int c = 0; c < 8; ++c) {
            int idx = c * 256 + t;
            int dv = idx >> 5, cc = idx & 31;
            bf16x8 v = zbf8();
            if (cc < 25) {
                v = *(const bf16x8*)(vb + (size_t)dv * 208 + cc * 8);
                if (cc == 24) { v[5] = (__bf16)0.f; v[6] = (__bf16)0.f; v[7] = (__bf16)0.f; }
            }
            *(bf16x8*)(lds + AVOFF + dv * 512 + ((cc * 16) ^ ((dv & 7) << 4))) = v;
        }
    }
    __syncthreads();

    const bf16t* qb = Qb + (size_t)bh * 197 * 64;
    char* olds = lds + AOOFF + wv * AOWAVE;

    for (int tt = wv; tt < 7; tt += 4) {
        const int i0 = tt * 32;
        int qrow = i0 + lr; if (qrow > 196) qrow = 196;
        bf16x8 qf[4];
#pragma unroll
        for (int s = 0; s < 4; ++s)
            qf[s] = *(const bf16x8*)(qb + (size_t)qrow * 64 + s * 16 + lk * 8);

        f32x16 acc[7];
#pragma unroll
        for (int kt = 0; kt < 7; ++kt) acc[kt] = zero16();
#pragma unroll
        for (int kt = 0; kt < 7; ++kt) {
#pragma unroll
            for (int s = 0; s < 4; ++s) {
                bf16x8 aK = *(const bf16x8*)(lds + AKOFF + (kt * 32 + lr) * 128
                                             + (((s * 16 + lk * 8) * 2) ^ xorv));
                acc[kt] = mfma_bf16(aK, qf[s], acc[kt]);
            }
        }
        float mx = -1e30f;
#pragma unroll
        for (int kt = 0; kt < 7; ++kt)
#pragma unroll
            for (int r = 0; r < 16; ++r) {
                int kk = kt * 32 + (r & 3) + 8 * (r >> 2) + 4 * lk;
                if (kk >= 197) acc[kt][r] = -1e30f;
                mx = fmaxf(mx, acc[kt][r]);
            }
        mx = fmaxf(mx, __shfl_xor(mx, 32));
        float sum = 0.f;
#pragma unroll
        for (int kt = 0; kt < 7; ++kt)
#pragma unroll
            for (int r = 0; r < 16; ++r) {
                float e = __expf((acc[kt][r] - mx) * 0.125f);
                acc[kt][r] = e;
                sum += e;
            }
        sum += __shfl_xor(sum, 32);
        float inv = 1.f / sum;

        f32x16 accO0 = zero16(), accO1 = zero16();
#pragma unroll
        for (int s = 0; s < 14; ++s) {
            const int kt = s >> 1, bb = (s & 1) * 8;
            unsigned A0 = pkbf(acc[kt][bb + 0], acc[kt][bb + 1]);
            unsigned A1 = pkbf(acc[kt][bb + 2], acc[kt][bb + 3]);
            unsigned C0 = pkbf(acc[kt][bb + 4], acc[kt][bb + 5]);
            unsigned C1 = pkbf(acc[kt][bb + 6], acc[kt][bb + 7]);
            unsigned x = lk ? A0 : C0, y = lk ? A1 : C1;
            unsigned rx = __shfl_xor(x, 32), ry = __shfl_xor(y, 32);
            union { unsigned u[4]; bf16x8 v; } fr;
            fr.u[0] = lk ? rx : A0; fr.u[1] = lk ? ry : A1;
            fr.u[2] = lk ? C0 : rx; fr.u[3] = lk ? C1 : ry;
            const int voff = ((s * 16 + lk * 8) * 2) ^ xorv;
            bf16x8 aV0 = *(const bf16x8*)(lds + AVOFF + lr * 512 + voff);
            bf16x8 aV1 = *(const bf16x8*)(lds + AVOFF + (lr + 32) * 512 + voff);
            accO0 = mfma_bf16(aV0, fr.v, accO0);
            accO1 = mfma_bf16(aV1, fr.v, accO1);
        }
#pragma unroll
        for (int r = 0; r < 16; r += 2) {
            int dvb = (r & 3) + 8 * (r >> 2) + 4 * lk;
            unsigned u0 = pkbf(accO0[r] * inv, accO0[r + 1] * inv);
            unsigned u1 = pkbf(accO1[r] * inv, accO1[r + 1] * inv);
            *(unsigned*)(olds + lr * AOSTR + dvb * 2) = u0;
            *(unsigned*)(olds + lr * AOSTR + (dvb + 32) * 2) = u1;
        }
        asm volatile("s_waitcnt lgkmcnt(0)" ::: "memory");
#pragma unroll
        for (int c = 0; c < 8; ++c) {
            int cid = c * 64 + lane;
            int q = cid >> 4, dc = cid & 15;
            bf16x4 v = *(const bf16x4*)(olds + q * AOSTR + dc * 8);
            int gq = i0 + q;
            if (gq < 197)
                *(bf16x4*)(att + ((size_t)b * 197 + gq) * 768 + h * 64 + dc * 4) = v;
        }
    }
}

extern "C" void kernel_launch(void* const* d_in, const int* in_sizes, int n_in,
                              void* d_out, int out_size, void* d_ws, size_t ws_size,
                              hipStream_t stream) {
    const float* x      = (const float*)d_in[0];
    const float* conv_w = (const float*)d_in[1];
    const float* conv_b = (const float*)d_in[2];
    const float* cls_e  = (const float*)d_in[3];
    const float* pos_e  = (const float*)d_in[4];
    const float* ln1_s  = (const float*)d_in[5];
    const float* ln1_b  = (const float*)d_in[6];
    const float* qkv_w  = (const float*)d_in[7];
    const float* qkv_b  = (const float*)d_in[8];
    const float* proj_w = (const float*)d_in[9];
    const float* proj_b = (const float*)d_in[10];
    const float* ln2_s  = (const float*)d_in[11];
    const float* ln2_b  = (const float*)d_in[12];
    const float* fc1_w  = (const float*)d_in[13];
    const float* fc1_b  = (const float*)d_in[14];
    const float* fc2_w  = (const float*)d_in[15];
    const float* fc2_b  = (const float*)d_in[16];

    // per-layer transposed-split weight elems (per half): qkv 2304*768, proj 768*768,
    // fc1 3072*768, fc2 3072*768
    const size_t QKV_E = 2304ull * 768, PRJ_E = 768ull * 768;
    const size_t FC1_E = 3072ull * 768, FC2_E = 3072ull * 768;
    const size_t perLayerE = QKV_E + PRJ_E + FC1_E + FC2_E;      // 7,077,888
    const size_t convE = 768ull * 768;
    const size_t wAllB = 12ull * perLayerE * 2 * 2;              // hi+lo, bf16
    const size_t wOneB = perLayerE * 2 * 2;
    const size_t convB = convE * 2 * 2;

    int imgs = BATCH;
    bool preAll = false;
    for (;;) {
        size_t act = (size_t)imgs * NTOK * 13824ull;
        if (act + convB + wAllB <= ws_size) { preAll = true; break; }
        if (act + convB + wOneB <= ws_size) { preAll = false; break; }
        if (imgs == 1) break;
        imgs >>= 1;
    }
    size_t Mr = (size_t)imgs * NTOK;

    float* h    = (float*)d_ws;
    bf16t* yhi  = (bf16t*)(h + Mr * 768);
    bf16t* ylo  = yhi + Mr * 768;
    bf16t* att  = ylo + Mr * 768;
    bf16t* big  = att + Mr * 768;            // Mr*3072 elems
    bf16t* cvH  = big + Mr * 3072;
    bf16t* cvL  = cvH + convE;
    bf16t* wb   = cvL + convE;

    // weight region layout (type-grouped, z-affine for batched transpose)
    bf16t *Qh, *Ql, *Ph, *Pl, *F1h, *F1l, *F2h, *F2l;
    if (preAll) {
        Qh = wb;            Ql = Qh + 12 * QKV_E;
        Ph = Ql + 12 * QKV_E; Pl = Ph + 12 * PRJ_E;
        F1h = Pl + 12 * PRJ_E; F1l = F1h + 12 * FC1_E;
        F2h = F1l + 12 * FC1_E; F2l = F2h + 12 * FC2_E;
    } else {
        Qh = wb;            Ql = Qh + QKV_E;
        Ph = Ql + QKV_E;    Pl = Ph + PRJ_E;
        F1h = Pl + PRJ_E;   F1l = F1h + FC1_E;
        F2h = F1l + FC1_E;  F2l = F2h + FC2_E;
    }

    // ---- weight prep ----
    esplit_k<<<(int)((convE + 255) / 256), 256, 0, stream>>>(conv_w, cvH, cvL, (int)convE);
    if (preAll) {
        tsplit_k<<<dim3(24, 6, 144), 256, 0, stream>>>(qkv_w, 768l * 192, Qh, Ql, 192l * 768, 768, 192);
        tsplit_k<<<dim3(24, 24, 12), 256, 0, stream>>>(proj_w, (long)PRJ_E, Ph, Pl, (long)PRJ_E, 768, 768);
        tsplit_k<<<dim3(24, 96, 12), 256, 0, stream>>>(fc1_w, (long)FC1_E, F1h, F1l, (long)FC1_E, 768, 3072);
        tsplit_k<<<dim3(96, 24, 12), 256, 0, stream>>>(fc2_w, (long)FC2_E, F2h, F2l, (long)FC2_E, 3072, 768);
    }

    int Mi = (int)Mr;
    int gy = (Mi + 127) / 128;
    size_t QKTOT = (size_t)imgs * 12 * 197 * 64;

    for (int b0 = 0; b0 < BATCH; b0 += imgs) {
        int Me = imgs * 196;
        // im2col emits split planes into yhi/ylo scratch (free before layer 0 LN)
        im2col_k<<<dim3((Me * 96 + 255) / 256), 256, 0, stream>>>(x, yhi, ylo, b0, Me);
        gemm_mfma<float, 3><<<dim3(6, (Me + 127) / 128), 256, 0, stream>>>(
            yhi, ylo, 768, cvH, cvL, conv_b, pos_e, h, 768, Me, 768, /*embedOut*/ 8);
        embed_cls<<<dim3(imgs), dim3(768), 0, stream>>>(cls_e, pos_e, h);

        for (int l = 0; l < LAYERS; ++l) {
            const bf16t *qh, *ql, *ph, *pl, *f1h, *f1l, *f2h, *f2l;
            if (preAll) {
                qh = Qh + (size_t)l * QKV_E;  ql = Ql + (size_t)l * QKV_E;
                ph = Ph + (size_t)l * PRJ_E;  pl = Pl + (size_t)l * PRJ_E;
                f1h = F1h + (size_t)l * FC1_E; f1l = F1l + (size_t)l * FC1_E;
                f2h = F2h + (size_t)l * FC2_E; f2l = F2l + (size_t)l * FC2_E;
            } else {
                tsplit_k<<<dim3(24, 6, 12), 256, 0, stream>>>(
                    qkv_w + (size_t)l * 12 * QKV_E / 12 * 1, 768l * 192, Qh, Ql, 192l * 768, 768, 192);
                tsplit_k<<<dim3(24, 24, 1), 256, 0, stream>>>(
                    proj_w + (size_t)l * PRJ_E, 0, Ph, Pl, 0, 768, 768);
                tsplit_k<<<dim3(24, 96, 1), 256, 0, stream>>>(
                    fc1_w + (size_t)l * FC1_E, 0, F1h, F1l, 0, 768, 3072);
                tsplit_k<<<dim3(96, 24, 1), 256, 0, stream>>>(
                    fc2_w + (size_t)l * FC2_E, 0, F2h, F2l, 0, 3072, 768);
                qh = Qh; ql = Ql; ph = Ph; pl = Pl;
                f1h = F1h; f1l = F1l; f2h = F2h; f2l = F2l;
            }
            const float* qb  = qkv_b  + (size_t)l * HEADS * 192;
            const float* pb  = proj_b + (size_t)l * 768;
            const float* f1b = fc1_b  + (size_t)l * 3072;
            const float* f2b = fc2_b  + (size_t)l * 768;

            layernorm_k<<<Mi, 256, 0, stream>>>(h, yhi, ylo, ln1_s + l * 768, ln1_b + l * 768);
            gemm_mfma<bf16t, 3><<<dim3(18, gy), 256, 0, stream>>>(
                yhi, ylo, 768, qh, ql, qb, nullptr, big, 2304, Mi, 768, /*qkvOut*/ 16);
            attn_mfma<<<dim3(imgs * 12), 256, 0, stream>>>(
                big, big + QKTOT, big + 2 * QKTOT, att);
            gemm_mfma<float, 2><<<dim3(6, gy), 256, 0, stream>>>(
                att, nullptr, 768, ph, pl, pb, h, h, 768, Mi, 768, 0);
            layernorm_k<<<Mi, 256, 0, stream>>>(h, yhi, ylo, ln2_s + l * 768, ln2_b + l * 768);
            gemm_mfma<bf16t, 3><<<dim3(24, gy), 256, 0, stream>>>(
                yhi, ylo, 768, f1h, f1l, f1b, nullptr, big, 3072, Mi, 768, /*gelu*/ 1);
            float* outC = (l == LAYERS - 1)
                        ? (float*)d_out + (size_t)b0 * NTOK * 768 : h;
            gemm_mfma<float, 2><<<dim3(6, gy), 256, 0, stream>>>(
                big, nullptr, 3072, f2h, f2l, f2b, h, outC, 768, Mi, 3072, 0);
        }
    }
}